// Round 2
// baseline (164.338 us; speedup 1.0000x reference)
//
#include <hip/hip_runtime.h>
#include <hip/hip_bf16.h>

typedef __bf16 bf16;
typedef bf16  bf16x8 __attribute__((ext_vector_type(8)));
typedef bf16  bf16x4 __attribute__((ext_vector_type(4)));
typedef float f32x4  __attribute__((ext_vector_type(4)));

#define MFMA16(A, Bv, Cv) __builtin_amdgcn_mfma_f32_16x16x32_bf16((A), (Bv), (Cv), 0, 0, 0)

namespace {
constexpr int   kB     = 2;
constexpr int   kS     = 2048;
constexpr int   kHq    = 16;
constexpr int   kHkv   = 8;
constexpr int   kD     = 128;
constexpr int   kChunk = 512;
constexpr int   kKB    = 64;    // keys per tile (= q rows per sub-tile)
constexpr float kScale = 0.08838834764831845f;  // 1/sqrt(128)
constexpr float kThr   = 8.0f;  // T13 defer-max threshold
}

// Per-sub-tile state: 16 q-rows per wave. o[8] is the row-sum (l) accumulated
// via a ones-column MFMA; m is the (deferred) running max.
struct St {
  bf16x8 qa[4];
  f32x4  o[9];
  float  m[4];
};

__device__ __forceinline__ void load_q(St& st, const float* __restrict__ qp, int l4) {
#pragma unroll
  for (int ks = 0; ks < 4; ++ks) {
    const float* p0 = qp + ks * 32 + 8 * l4;
    f32x4 x0 = *(const f32x4*)(p0);
    f32x4 x1 = *(const f32x4*)(p0 + 4);
    bf16x8 qv;
#pragma unroll
    for (int j = 0; j < 4; ++j) {
      qv[j]     = (bf16)(x0[j] * kScale);
      qv[j + 4] = (bf16)(x1[j] * kScale);
    }
    st.qa[ks] = qv;
  }
  const f32x4 z = {0.f, 0.f, 0.f, 0.f};
#pragma unroll
  for (int dt = 0; dt < 9; ++dt) st.o[dt] = z;
#pragma unroll
  for (int r = 0; r < 4; ++r) st.m[r] = -1e30f;
}

// Mask (if diag), tile max, T13 deferred rescale, exp, P store (D->A relayout).
__device__ __forceinline__ void softmax_store(St& st, f32x4 (&sacc)[4], bool diag,
                                              int w, int l4, int l15,
                                              bf16 (&P)[16][72]) {
  float sv[4][4];
#pragma unroll
  for (int kb = 0; kb < 4; ++kb)
#pragma unroll
    for (int r = 0; r < 4; ++r) sv[kb][r] = sacc[kb][r];
  if (diag) {
#pragma unroll
    for (int kb = 0; kb < 4; ++kb) {
      const int keyl = kb * 16 + l15;
#pragma unroll
      for (int r = 0; r < 4; ++r) {
        const int rowl = w * 16 + l4 * 4 + r;
        if (keyl > rowl) sv[kb][r] = -1e30f;
      }
    }
  }
  float mx[4];
#pragma unroll
  for (int r = 0; r < 4; ++r)
    mx[r] = fmaxf(fmaxf(sv[0][r], sv[1][r]), fmaxf(sv[2][r], sv[3][r]));
#pragma unroll
  for (int off = 1; off < 16; off <<= 1) {
#pragma unroll
    for (int r = 0; r < 4; ++r) mx[r] = fmaxf(mx[r], __shfl_xor(mx[r], off, 64));
  }
  // T13: only rescale when the tile max outgrows the deferred bound.
  const bool grow = (mx[0] > st.m[0] + kThr) || (mx[1] > st.m[1] + kThr) ||
                    (mx[2] > st.m[2] + kThr) || (mx[3] > st.m[3] + kThr);
  if (__any(grow)) {
    float corr[4];
#pragma unroll
    for (int r = 0; r < 4; ++r) {
      const float mn = fmaxf(st.m[r], mx[r]);
      corr[r] = __expf(st.m[r] - mn);
      st.m[r] = mn;
    }
#pragma unroll
    for (int dt = 0; dt < 9; ++dt)
#pragma unroll
      for (int r = 0; r < 4; ++r) st.o[dt][r] *= corr[r];
  }
#pragma unroll
  for (int kb = 0; kb < 4; ++kb)
#pragma unroll
    for (int r = 0; r < 4; ++r)
      P[l4 * 4 + r][kb * 16 + l15] = (bf16)__expf(sv[kb][r] - st.m[r]);
}

// One 64-key tile for sub-tile B (always) and A (if DUAL), sharing K/V frags.
template <bool DUAL>
__device__ __forceinline__ void tile_step(St& sB, St& sA, bool diagB, bool diagA,
                                          int w, int l4, int l15,
                                          const bf16* __restrict__ ldsK,
                                          const bf16* __restrict__ ldsV,
                                          bf16 (&PB)[16][72], bf16 (&PA)[16][72],
                                          bf16x8 ones) {
  const f32x4 z = {0.f, 0.f, 0.f, 0.f};
  f32x4 accB[4], accA[4];
#pragma unroll
  for (int kb = 0; kb < 4; ++kb) { accB[kb] = z; if (DUAL) accA[kb] = z; }
  __builtin_amdgcn_s_setprio(1);
#pragma unroll
  for (int kb = 0; kb < 4; ++kb) {
    const int key = kb * 16 + l15;
    const int swz = (key & 7) << 3;
#pragma unroll
    for (int ks = 0; ks < 4; ++ks) {
      bf16x8 kfrag = *(const bf16x8*)(&ldsK[key * 128 + ((ks * 32 + 8 * l4) ^ swz)]);
      accB[kb] = MFMA16(sB.qa[ks], kfrag, accB[kb]);
      if (DUAL) accA[kb] = MFMA16(sA.qa[ks], kfrag, accA[kb]);
    }
  }
  __builtin_amdgcn_s_setprio(0);
  softmax_store(sB, accB, diagB, w, l4, l15, PB);
  if (DUAL) softmax_store(sA, accA, diagA, w, l4, l15, PA);
  bf16x8 pB[2], pA[2];
#pragma unroll
  for (int kk = 0; kk < 2; ++kk) {
    pB[kk] = *(const bf16x8*)(&PB[l15][kk * 32 + 8 * l4]);
    if (DUAL) pA[kk] = *(const bf16x8*)(&PA[l15][kk * 32 + 8 * l4]);
  }
  __builtin_amdgcn_s_setprio(1);
#pragma unroll
  for (int dt = 0; dt < 8; ++dt) {
    const int d   = dt * 16 + l15;
    const int swz = (d & 7) << 3;
#pragma unroll
    for (int kk = 0; kk < 2; ++kk) {
      bf16x8 vb = *(const bf16x8*)(&ldsV[d * 64 + ((kk * 32 + 8 * l4) ^ swz)]);
      sB.o[dt] = MFMA16(pB[kk], vb, sB.o[dt]);
      if (DUAL) sA.o[dt] = MFMA16(pA[kk], vb, sA.o[dt]);
    }
  }
#pragma unroll
  for (int kk = 0; kk < 2; ++kk) {  // row-sum (l) via ones column
    sB.o[8] = MFMA16(pB[kk], ones, sB.o[8]);
    if (DUAL) sA.o[8] = MFMA16(pA[kk], ones, sA.o[8]);
  }
  __builtin_amdgcn_s_setprio(0);
}

__device__ __forceinline__ void epilogue(const St& st, int qt, int b, int n, int hq,
                                         int w, int l4, int l15,
                                         float* __restrict__ Og) {
#pragma unroll
  for (int r = 0; r < 4; ++r) {
    const float lsum = __shfl(st.o[8][r], l4 << 4, 64);  // l lives at l15==0
    const float inv  = 1.f / lsum;
    const int   srow = n * kChunk + qt * kKB + w * 16 + l4 * 4 + r;
    float* op = Og + (((size_t)(b * kS + srow) * kHq + hq) * kD);
#pragma unroll
    for (int dt = 0; dt < 8; ++dt) op[dt * 16 + l15] = st.o[dt][r] * inv;
  }
}

// Block = (b, n, hq, qp): sub-tile A = q-tile qp, sub-tile B = q-tile 7-qp.
// Uniform 9 compute-tiles per block; K/V staged max(qtB)+1 = 8-qp tiles.
__global__ __launch_bounds__(256, 2)
void attn_chunk(const float* __restrict__ Qg, const float* __restrict__ Kg,
                const float* __restrict__ Vg, float* __restrict__ Og) {
  __shared__ __attribute__((aligned(16))) bf16 ldsK[kKB * 128];
  __shared__ __attribute__((aligned(16))) bf16 ldsV[128 * kKB];
  __shared__ __attribute__((aligned(16))) bf16 ldsP[4][2][16][72];

  const int t    = threadIdx.x;
  const int lane = t & 63;
  const int w    = t >> 6;
  const int l15  = lane & 15;
  const int l4   = lane >> 4;

  // XCD-aware bijective swizzle (gridDim 512, 512 % 8 == 0).
  const int gid0 = blockIdx.x;
  const int gid  = (gid0 & 7) * ((int)gridDim.x >> 3) + (gid0 >> 3);

  const int qp = gid & 3;
  const int hq = (gid >> 2) & 15;
  const int n  = (gid >> 6) & 3;
  const int b  = (gid >> 8) & 1;
  const int h  = hq >> 1;  // kv head (G=2)
  const int qtA = qp, qtB = 7 - qp;

  St sA, sB;
  {
    const int rA = n * kChunk + qtA * kKB + w * 16 + l15;
    load_q(sA, Qg + (((size_t)(b * kS + rA) * kHq + hq) * kD), l4);
    const int rB = n * kChunk + qtB * kKB + w * 16 + l15;
    load_q(sB, Qg + (((size_t)(b * kS + rB) * kHq + hq) * kD), l4);
  }
  bf16x8 ones;
#pragma unroll
  for (int j = 0; j < 8; ++j) ones[j] = (l15 == 0) ? (bf16)1.0f : (bf16)0.0f;

  const float* kpz = Kg + ((size_t)(b * kS + n * kChunk) * kHkv + h) * kD;
  const float* vpz = Vg + ((size_t)(b * kS + n * kChunk) * kHkv + h) * kD;

  // T14: register prefetch of tile kt, written to LDS at loop top.
  f32x4 kf[8], vf[8];
#pragma unroll
  for (int it = 0; it < 8; ++it) {
    const int idx = it * 256 + t;
    kf[it] = *(const f32x4*)(kpz + (size_t)(idx >> 5) * (kHkv * kD) + (idx & 31) * 4);
    vf[it] = *(const f32x4*)(vpz + (size_t)(idx & 63) * (kHkv * kD) + (idx >> 6) * 4);
  }

  for (int kt = 0; kt <= qtB; ++kt) {
    __syncthreads();  // all reads of previous LDS tile done
#pragma unroll
    for (int it = 0; it < 8; ++it) {  // K: [key][d], swizzled
      const int idx = it * 256 + t;
      const int key = idx >> 5, d4 = idx & 31;
      bf16x4 kb4;
#pragma unroll
      for (int j = 0; j < 4; ++j) kb4[j] = (bf16)kf[it][j];
      *(bf16x4*)(&ldsK[key * 128 + ((d4 * 4) ^ ((key & 7) << 3))]) = kb4;
    }
#pragma unroll
    for (int it = 0; it < 8; ++it) {  // V: transposed [d][key], swizzled
      const int idx = it * 256 + t;
      const int key = idx & 63, d4 = idx >> 6;
#pragma unroll
      for (int j = 0; j < 4; ++j) {
        const int d = d4 * 4 + j;
        ldsV[d * 64 + (key ^ ((d & 7) << 3))] = (bf16)vf[it][j];
      }
    }
    __syncthreads();
    if (kt < qtB) {  // issue next tile's loads; latency hides under compute
      const float* kp = kpz + (size_t)(kt + 1) * kKB * (kHkv * kD);
      const float* vp = vpz + (size_t)(kt + 1) * kKB * (kHkv * kD);
#pragma unroll
      for (int it = 0; it < 8; ++it) {
        const int idx = it * 256 + t;
        kf[it] = *(const f32x4*)(kp + (size_t)(idx >> 5) * (kHkv * kD) + (idx & 31) * 4);
        vf[it] = *(const f32x4*)(vp + (size_t)(idx & 63) * (kHkv * kD) + (idx >> 6) * 4);
      }
    }
    if (kt <= qtA)
      tile_step<true>(sB, sA, kt == qtB, kt == qtA, w, l4, l15, ldsK, ldsV,
                      ldsP[w][0], ldsP[w][1], ones);
    else
      tile_step<false>(sB, sA, kt == qtB, false, w, l4, l15, ldsK, ldsV,
                       ldsP[w][0], ldsP[w][1], ones);
  }

  epilogue(sB, qtB, b, n, hq, w, l4, l15, Og);
  epilogue(sA, qtA, b, n, hq, w, l4, l15, Og);
}

extern "C" void kernel_launch(void* const* d_in, const int* in_sizes, int n_in,
                              void* d_out, int out_size, void* d_ws, size_t ws_size,
                              hipStream_t stream) {
  (void)in_sizes; (void)n_in; (void)d_ws; (void)ws_size; (void)out_size;
  const float* Q = (const float*)d_in[0];
  const float* K = (const float*)d_in[1];
  const float* V = (const float*)d_in[2];
  float* O = (float*)d_out;
  dim3 grid(kB * (kS / kChunk) * kHq * 4);  // 512 blocks, uniform work
  dim3 block(256);
  hipLaunchKernelGGL(attn_chunk, grid, block, 0, stream, Q, K, V, O);
}

// Round 3
// 107.843 us; speedup vs baseline: 1.5239x; 1.5239x over previous
//
#include <hip/hip_runtime.h>
#include <hip/hip_bf16.h>

typedef __bf16 bf16;
typedef bf16  bf16x8 __attribute__((ext_vector_type(8)));
typedef bf16  bf16x4 __attribute__((ext_vector_type(4)));
typedef float f32x4  __attribute__((ext_vector_type(4)));

#define MFMA16(A, Bv, Cv) __builtin_amdgcn_mfma_f32_16x16x32_bf16((A), (Bv), (Cv), 0, 0, 0)

namespace {
constexpr int   kB = 2, kS = 2048, kHq = 16, kHkv = 8, kD = 128, kChunk = 512, kKB = 64;
constexpr int   kKVStride = kHkv * kD;  // floats between consecutive keys
constexpr float kScale = 0.08838834764831845f;  // 1/sqrt(128)
constexpr float kThr   = 8.0f;                  // T13 defer-max threshold
}

// Chunked-causal GQA flash attention. Grid 1024 = (b,n,hq,qt); 4 waves x 16 q-rows.
// T14: K(kt+1)/V(kt+1) register-prefetched under compute (fits in 170-VGPR cap).
__global__ __launch_bounds__(256, 3)
void attn_chunk(const float* __restrict__ Qg, const float* __restrict__ Kg,
                const float* __restrict__ Vg, float* __restrict__ Og) {
  __shared__ __attribute__((aligned(16))) bf16 ldsK[kKB * 128];   // [key][d] swizzled
  __shared__ __attribute__((aligned(16))) bf16 ldsV[128 * kKB];   // [d][key] swizzled
  __shared__ __attribute__((aligned(16))) bf16 ldsP[4][16][72];   // per-wave P relayout

  const int t = threadIdx.x, lane = t & 63, w = t >> 6, l15 = lane & 15, l4 = lane >> 4;

  // XCD bucket of 128 blocks = one (b,n): K/V working set 4 MB = one XCD L2.
  const int gid = (blockIdx.x & 7) * 128 + (blockIdx.x >> 3);
  const int qt  = 7 - (gid & 7);  // long (8-tile) blocks dispatch first
  const int hq  = (gid >> 3) & 15;
  const int n   = (gid >> 7) & 3;
  const int b   = (gid >> 9) & 1;
  const int h   = hq >> 1;  // kv head (G=2)

  // ---- Q fragments (A-layout: row=l15, k=8*l4+j), scale folded ----
  bf16x8 qa[4];
  {
    const int    s_q = n * kChunk + qt * kKB + w * 16 + l15;
    const float* qp  = Qg + ((size_t)(b * kS + s_q) * kHq + hq) * kD;
#pragma unroll
    for (int ks = 0; ks < 4; ++ks) {
      f32x4 x0 = *(const f32x4*)(qp + ks * 32 + 8 * l4);
      f32x4 x1 = *(const f32x4*)(qp + ks * 32 + 8 * l4 + 4);
      bf16x8 qv;
#pragma unroll
      for (int j = 0; j < 4; ++j) { qv[j] = (bf16)(x0[j] * kScale); qv[j + 4] = (bf16)(x1[j] * kScale); }
      qa[ks] = qv;
    }
  }
  f32x4 o[9];  // o[0..7] = O cols, o[8] = row-sum l via ones-column MFMA
  float m[4];
  const f32x4 z4 = {0.f, 0.f, 0.f, 0.f};
#pragma unroll
  for (int i = 0; i < 9; ++i) o[i] = z4;
#pragma unroll
  for (int r = 0; r < 4; ++r) m[r] = -1e30f;

  bf16x8 ones;
#pragma unroll
  for (int j = 0; j < 8; ++j) ones[j] = (l15 == 0) ? (bf16)1.0f : (bf16)0.0f;

  const float* kpz = Kg + ((size_t)(b * kS + n * kChunk) * kHkv + h) * kD;
  const float* vpz = Vg + ((size_t)(b * kS + n * kChunk) * kHkv + h) * kD;

  // staging coordinates: K: key=8*it+(t>>5), d4=t&31 ; V: key=lane, d4=4*it+w
  const int kKey0 = t >> 5, kD4 = t & 31;
  const int vKey  = t & 63, vW = w;

  // ---- preload tile 0 into registers ----
  f32x4 kf[8], vf[8];
#pragma unroll
  for (int it = 0; it < 8; ++it) {
    kf[it] = *(const f32x4*)(kpz + (size_t)(8 * it + kKey0) * kKVStride + kD4 * 4);
    vf[it] = *(const f32x4*)(vpz + (size_t)vKey * kKVStride + (4 * it + vW) * 4);
  }

  for (int kt = 0;; ++kt) {
    // ---- stage-write: consume kf/vf(kt) -> LDS bf16 ----
#pragma unroll
    for (int it = 0; it < 8; ++it) {
      const int key = 8 * it + kKey0;
      bf16x4 kb4;
#pragma unroll
      for (int j = 0; j < 4; ++j) kb4[j] = (bf16)kf[it][j];
      *(bf16x4*)(&ldsK[key * 128 + ((kD4 * 4) ^ ((key & 7) << 3))]) = kb4;
    }
#pragma unroll
    for (int it = 0; it < 8; ++it) {
#pragma unroll
      for (int j = 0; j < 4; ++j) {
        const int d = (4 * it + vW) * 4 + j;
        ldsV[d * 64 + (vKey ^ ((d & 7) << 3))] = (bf16)vf[it][j];
      }
    }
    __syncthreads();

    const bool more = (kt < qt);
    if (more) {  // T14: K(kt+1) in flight under QK^T..PV
      const float* kp = kpz + (size_t)(kt + 1) * kKB * kKVStride;
#pragma unroll
      for (int it = 0; it < 8; ++it)
        kf[it] = *(const f32x4*)(kp + (size_t)(8 * it + kKey0) * kKVStride + kD4 * 4);
    }

    // ---- QK^T: 16 q-rows x 64 keys (16 MFMA) ----
    f32x4 acc[4];
#pragma unroll
    for (int kb = 0; kb < 4; ++kb) acc[kb] = z4;
    __builtin_amdgcn_s_setprio(1);
#pragma unroll
    for (int kb = 0; kb < 4; ++kb) {
      const int key = kb * 16 + l15;
      const int swz = (key & 7) << 3;
#pragma unroll
      for (int ks = 0; ks < 4; ++ks) {
        bf16x8 kfrag = *(const bf16x8*)(&ldsK[key * 128 + ((ks * 32 + 8 * l4) ^ swz)]);
        acc[kb] = MFMA16(qa[ks], kfrag, acc[kb]);
      }
    }
    __builtin_amdgcn_s_setprio(0);

    if (more) {  // T14: V(kt+1) in flight under softmax+PV
      const float* vp = vpz + (size_t)(kt + 1) * kKB * kKVStride;
#pragma unroll
      for (int it = 0; it < 8; ++it)
        vf[it] = *(const f32x4*)(vp + (size_t)vKey * kKVStride + (4 * it + vW) * 4);
    }

    // ---- masked online softmax (D-layout rows = l4*4+r) ----
    const bool diag = (kt == qt);
    if (diag) {
#pragma unroll
      for (int kb = 0; kb < 4; ++kb) {
        const int keyl = kb * 16 + l15;
#pragma unroll
        for (int r = 0; r < 4; ++r)
          if (keyl > w * 16 + l4 * 4 + r) acc[kb][r] = -1e30f;
      }
    }
    float mx[4];
#pragma unroll
    for (int r = 0; r < 4; ++r)
      mx[r] = fmaxf(fmaxf(acc[0][r], acc[1][r]), fmaxf(acc[2][r], acc[3][r]));
#pragma unroll
    for (int off = 1; off < 16; off <<= 1)
#pragma unroll
      for (int r = 0; r < 4; ++r) mx[r] = fmaxf(mx[r], __shfl_xor(mx[r], off, 64));

    // T13 defer-max: rescale only when tile max outgrows bound (exp(thr) headroom)
    const bool grow = (mx[0] > m[0] + kThr) || (mx[1] > m[1] + kThr) ||
                      (mx[2] > m[2] + kThr) || (mx[3] > m[3] + kThr);
    if (__any(grow)) {
      float corr[4];
#pragma unroll
      for (int r = 0; r < 4; ++r) {
        const float mn = fmaxf(m[r], mx[r]);
        corr[r] = __expf(m[r] - mn);
        m[r]    = mn;
      }
#pragma unroll
      for (int i = 0; i < 9; ++i)
#pragma unroll
        for (int r = 0; r < 4; ++r) o[i][r] *= corr[r];
    }
#pragma unroll
    for (int kb = 0; kb < 4; ++kb)
#pragma unroll
      for (int r = 0; r < 4; ++r)
        ldsP[w][l4 * 4 + r][kb * 16 + l15] = (bf16)__expf(acc[kb][r] - m[r]);

    // ---- PV (16 MFMA) + row-sum (2 MFMA) ----
    bf16x8 pa[2];
#pragma unroll
    for (int kk = 0; kk < 2; ++kk)
      pa[kk] = *(const bf16x8*)(&ldsP[w][l15][kk * 32 + 8 * l4]);
    __builtin_amdgcn_s_setprio(1);
#pragma unroll
    for (int dt = 0; dt < 8; ++dt) {
      const int d   = dt * 16 + l15;
      const int swz = (d & 7) << 3;
#pragma unroll
      for (int kk = 0; kk < 2; ++kk) {
        bf16x8 vb = *(const bf16x8*)(&ldsV[d * 64 + ((kk * 32 + 8 * l4) ^ swz)]);
        o[dt] = MFMA16(pa[kk], vb, o[dt]);
      }
    }
#pragma unroll
    for (int kk = 0; kk < 2; ++kk) o[8] = MFMA16(pa[kk], ones, o[8]);
    __builtin_amdgcn_s_setprio(0);

    if (!more) break;
    __syncthreads();  // all LDS reads done before next stage-write
  }

  // ---- epilogue: O / l (l lives in acc col 0 => lane l15==0) ----
#pragma unroll
  for (int r = 0; r < 4; ++r) {
    const float lsum = __shfl(o[8][r], l4 << 4, 64);
    const float inv  = 1.f / lsum;
    const int   srow = n * kChunk + qt * kKB + w * 16 + l4 * 4 + r;
    float* op = Og + ((size_t)(b * kS + srow) * kHq + hq) * kD;
#pragma unroll
    for (int dt = 0; dt < 8; ++dt) op[dt * 16 + l15] = o[dt][r] * inv;
  }
}

extern "C" void kernel_launch(void* const* d_in, const int* in_sizes, int n_in,
                              void* d_out, int out_size, void* d_ws, size_t ws_size,
                              hipStream_t stream) {
  (void)in_sizes; (void)n_in; (void)d_ws; (void)ws_size; (void)out_size;
  const float* Q = (const float*)d_in[0];
  const float* K = (const float*)d_in[1];
  const float* V = (const float*)d_in[2];
  float* O = (float*)d_out;
  dim3 grid(kB * (kS / kChunk) * kHq * (kChunk / kKB));  // 1024
  dim3 block(256);
  hipLaunchKernelGGL(attn_chunk, grid, block, 0, stream, Q, K, V, O);
}

// Round 4
// 34.960 us; speedup vs baseline: 4.7007x; 3.0847x over previous
//
#include <hip/hip_runtime.h>
#include <hip/hip_bf16.h>

typedef __bf16 bf16;
typedef bf16  bf16x2 __attribute__((ext_vector_type(2)));
typedef bf16  bf16x4 __attribute__((ext_vector_type(4)));
typedef bf16  bf16x8 __attribute__((ext_vector_type(8)));
typedef float f32x4  __attribute__((ext_vector_type(4)));
typedef float f32x16 __attribute__((ext_vector_type(16)));

#define MFMA32(A, B, C) __builtin_amdgcn_mfma_f32_32x32x16_bf16((A), (B), (C), 0, 0, 0)

namespace {
constexpr int   kS = 2048, kHq = 16, kHkv = 8, kD = 128, kChunk = 512;
constexpr int   kNT   = 8;            // kv tiles of 64 per chunk
constexpr int   kStrK = kHkv * kD;    // floats between consecutive keys (1024)
constexpr float kScale = 0.08838834764831845f;  // 1/sqrt(128)
constexpr float kThr   = 8.0f;                  // T13 defer-max threshold
}

union U32B { bf16x2 h; unsigned u; };
union PAU  { unsigned u[4]; bf16x8 v; };

// Swapped-QK^T chunked-causal GQA attention (m214 structure).
// 256 blocks (b,n,hq,p) x 512 threads (8 waves, 32 q-rows each).
// S^T = K*Q^T  -> lane owns q = lane&31; softmax lane-local.
// O^T = V^T*P^T -> q stays lane-local for rescale/divide.
__global__ __launch_bounds__(512, 2)
void attn_chunk(const float* __restrict__ Qg, const float* __restrict__ Kg,
                const float* __restrict__ Vg, float* __restrict__ Og) {
  __shared__ __attribute__((aligned(16))) bf16 ldsK[2][64 * 128];  // [key][d]  ^((key&7)<<3)
  __shared__ __attribute__((aligned(16))) bf16 ldsV[2][128 * 64];  // [d][key]  ^((d&7)<<3)

  const int t = threadIdx.x, lane = t & 63, w = t >> 6;
  const int l31 = lane & 31, hi = lane >> 5;

  // XCD grouping: all 32 blocks of one (b,n) land on one XCD (K/V ~4MB = L2).
  const int bid = blockIdx.x;
  const int gid = (bid & 7) * 32 + (bid >> 3);
  const int p = gid & 1, hq = (gid >> 1) & 15, n = (gid >> 5) & 3, b = (gid >> 7) & 1;
  const int h = hq >> 1;

  // Per-SIMD balanced strip assignment: waves (w, w+4) need 9 tiles together.
  const int a     = (w < 4) ? (7 - 2 * w) : (2 * w - 8);
  const int need  = a + 1;          // kv tiles this wave computes
  const int strip = 2 * a + p;      // 32-row q-strip index within chunk
  const int qg    = n * kChunk + strip * 32 + l31;  // global q row (lane-local)
  const int rowoff = 32 * p + l31;  // q offset within diagonal 64-key tile

  // ---- Q fragments: B-operand, col=q=l31, k = dk*16 + 8*hi + j ----
  bf16x8 qf[8];
  {
    const float* qp = Qg + ((size_t)(b * kS + qg) * kHq + hq) * kD;
#pragma unroll
    for (int dk = 0; dk < 8; ++dk) {
      f32x4 x0 = *(const f32x4*)(qp + dk * 16 + 8 * hi);
      f32x4 x1 = *(const f32x4*)(qp + dk * 16 + 8 * hi + 4);
      bf16x8 v;
#pragma unroll
      for (int j = 0; j < 4; ++j) { v[j] = (bf16)(x0[j] * kScale); v[4 + j] = (bf16)(x1[j] * kScale); }
      qf[dk] = v;
    }
  }

  f32x16 o[4];  // O^T accum: d = 32*dt + (r&3)+8*(r>>2)+4*hi, col q = l31
#pragma unroll
  for (int dt = 0; dt < 4; ++dt)
#pragma unroll
    for (int r = 0; r < 16; ++r) o[dt][r] = 0.f;
  float m = -1e30f, l = 0.f;

  const float* kpz = Kg + ((size_t)(b * kS + n * kChunk) * kHkv + h) * kD;
  const float* vpz = Vg + ((size_t)(b * kS + n * kChunk) * kHkv + h) * kD;

  // staging coords (512 threads): K coalesced rows; V keypair loads, b32 writes
  const int sKey = t >> 5, sD4 = t & 31;   // K: key = 16*it + sKey
  const int vKp = t & 31, vD4h = t >> 5;   // V: keys {2vKp,2vKp+1}, d4 = 16*it + vD4h

  f32x4 kf[4], va[2], vb[2];  // 2-deep T14 prefetch registers
  auto issue = [&](int kt) {
    const float* kp = kpz + (size_t)kt * 64 * kStrK;
    const float* vp = vpz + (size_t)kt * 64 * kStrK;
#pragma unroll
    for (int it = 0; it < 4; ++it)
      kf[it] = *(const f32x4*)(kp + (size_t)(16 * it + sKey) * kStrK + sD4 * 4);
#pragma unroll
    for (int it = 0; it < 2; ++it) {
      va[it] = *(const f32x4*)(vp + (size_t)(2 * vKp) * kStrK + (16 * it + vD4h) * 4);
      vb[it] = *(const f32x4*)(vp + (size_t)(2 * vKp + 1) * kStrK + (16 * it + vD4h) * 4);
    }
  };
  auto stage = [&](int buf) {
#pragma unroll
    for (int it = 0; it < 4; ++it) {
      const int key = 16 * it + sKey;
      bf16x4 kb;
#pragma unroll
      for (int j = 0; j < 4; ++j) kb[j] = (bf16)kf[it][j];
      *(bf16x4*)&ldsK[buf][key * 128 + ((sD4 * 4) ^ ((key & 7) << 3))] = kb;
    }
#pragma unroll
    for (int it = 0; it < 2; ++it) {
#pragma unroll
      for (int j = 0; j < 4; ++j) {
        const int d = (16 * it + vD4h) * 4 + j;
        U32B uu; uu.h = bf16x2{(bf16)va[it][j], (bf16)vb[it][j]};
        *(unsigned*)&ldsV[buf][d * 64 + ((2 * vKp) ^ ((d & 7) << 3))] = uu.u;
      }
    }
  };

  auto compute = [&](int buf, bool diag) {
    // ---- QK^T: S^T[key][q], 16 MFMA ----
    f32x16 s[2];
#pragma unroll
    for (int ks = 0; ks < 2; ++ks)
#pragma unroll
      for (int r = 0; r < 16; ++r) s[ks][r] = 0.f;
    __builtin_amdgcn_s_setprio(1);
#pragma unroll
    for (int ks = 0; ks < 2; ++ks) {
      const int key = ks * 32 + l31, swz = (key & 7) << 3;
      const bf16* kb = &ldsK[buf][key * 128];
#pragma unroll
      for (int dk = 0; dk < 8; ++dk) {
        bf16x8 kfr = *(const bf16x8*)&kb[(dk * 16 + 8 * hi) ^ swz];
        s[ks] = MFMA32(kfr, qf[dk], s[ks]);
      }
    }
    __builtin_amdgcn_s_setprio(0);
    if (diag) {
#pragma unroll
      for (int ks = 0; ks < 2; ++ks)
#pragma unroll
        for (int r = 0; r < 16; ++r) {
          const int key = ks * 32 + (r & 3) + 8 * (r >> 2) + 4 * hi;
          if (key > rowoff) s[ks][r] = -1e30f;
        }
    }
    // ---- lane-local softmax (q = l31; partner = lane^32) ----
    float mx = -1e30f;
#pragma unroll
    for (int ks = 0; ks < 2; ++ks)
#pragma unroll
      for (int r = 0; r < 16; ++r) mx = fmaxf(mx, s[ks][r]);
    mx = fmaxf(mx, __shfl_xor(mx, 32, 64));
    if (__any(mx > m + kThr)) {  // T13 defer-max
      const float mn = fmaxf(m, mx), c = __expf(m - mn);
      l *= c;
#pragma unroll
      for (int dt = 0; dt < 4; ++dt)
#pragma unroll
        for (int r = 0; r < 16; ++r) o[dt][r] *= c;
      m = mn;
    }
    unsigned u[2][8];
    float lp = 0.f;
#pragma unroll
    for (int ks = 0; ks < 2; ++ks)
#pragma unroll
      for (int j = 0; j < 8; ++j) {
        const float p0 = __expf(s[ks][2 * j] - m), p1 = __expf(s[ks][2 * j + 1] - m);
        lp += p0 + p1;
        U32B uu; uu.h = bf16x2{(bf16)p0, (bf16)p1};
        u[ks][j] = uu.u;
      }
    l += lp;
    // ---- half-exchange: interleaved-4 ownership -> contiguous-8 B-frags ----
    unsigned rc[2][4];
#pragma unroll
    for (int ks = 0; ks < 2; ++ks)
#pragma unroll
      for (int i = 0; i < 4; ++i)
        rc[ks][i] = (unsigned)__shfl_xor((int)u[ks][(i & 1) + 4 * (i >> 1) + (hi ? 0 : 2)], 32, 64);
    bf16x8 pa[4];
#pragma unroll
    for (int ks = 0; ks < 2; ++ks)
#pragma unroll
      for (int kh = 0; kh < 2; ++kh) {
        PAU pu;
        pu.u[0] = hi ? rc[ks][2 * kh]     : u[ks][4 * kh];
        pu.u[1] = hi ? rc[ks][2 * kh + 1] : u[ks][4 * kh + 1];
        pu.u[2] = hi ? u[ks][4 * kh + 2]  : rc[ks][2 * kh];
        pu.u[3] = hi ? u[ks][4 * kh + 3]  : rc[ks][2 * kh + 1];
        pa[ks * 2 + kh] = pu.v;
      }
    // ---- PV: O^T += V^T * P^T, 16 MFMA ----
    __builtin_amdgcn_s_setprio(1);
#pragma unroll
    for (int dt = 0; dt < 4; ++dt) {
      const int d = dt * 32 + l31, swz = (d & 7) << 3;
      const bf16* vbp = &ldsV[buf][d * 64];
#pragma unroll
      for (int ksl = 0; ksl < 4; ++ksl) {
        bf16x8 vfr = *(const bf16x8*)&vbp[(ksl * 16 + 8 * hi) ^ swz];
        o[dt] = MFMA32(vfr, pa[ksl], o[dt]);
      }
    }
    __builtin_amdgcn_s_setprio(0);
  };

  // ---- main loop: 1 barrier/tile, double-buffered LDS, 2-deep prefetch ----
  issue(0);
  stage(0);
  issue(1);
  __syncthreads();
#pragma unroll 1
  for (int kt = 0; kt < kNT; ++kt) {
    if (kt + 1 < kNT) {
      stage((kt + 1) & 1);
      if (kt + 2 < kNT) issue(kt + 2);
    }
    if (kt < need) compute(kt & 1, kt == need - 1);
    if (kt + 1 < kNT) __syncthreads();
  }

  // ---- epilogue: combine partner l, divide, store O^T regs (f32x4 packed) ----
  l += __shfl_xor(l, 32, 64);
  const float inv = 1.f / l;
  float* op = Og + ((size_t)(b * kS + qg) * kHq + hq) * kD;
#pragma unroll
  for (int dt = 0; dt < 4; ++dt)
#pragma unroll
    for (int rq = 0; rq < 4; ++rq) {
      f32x4 st;
#pragma unroll
      for (int rr = 0; rr < 4; ++rr) st[rr] = o[dt][4 * rq + rr] * inv;
      *(f32x4*)(op + dt * 32 + 8 * rq + 4 * hi) = st;
    }
}

extern "C" void kernel_launch(void* const* d_in, const int* in_sizes, int n_in,
                              void* d_out, int out_size, void* d_ws, size_t ws_size,
                              hipStream_t stream) {
  (void)in_sizes; (void)n_in; (void)d_ws; (void)ws_size; (void)out_size;
  const float* Q = (const float*)d_in[0];
  const float* K = (const float*)d_in[1];
  const float* V = (const float*)d_in[2];
  float* O = (float*)d_out;
  dim3 grid(256);   // (b2, n4, hq16, p2), XCD-grouped
  dim3 block(512);  // 8 waves x 32 q-rows
  hipLaunchKernelGGL(attn_chunk, grid, block, 0, stream, Q, K, V, O);
}